// Round 1
// baseline (2245.188 us; speedup 1.0000x reference)
//
#include <hip/hip_runtime.h>
#include <hip/hip_fp16.h>

#define DS 256   // state_dim
#define DA 16    // act_dim
#define DH 30    // horizon
#define DHY 64   // hyper_dim
#define DB 64    // batch
#define DT 64    // seq len

// ---------------- setup kernels ----------------

// h_dist[b,h] = softmax_h((h+1)*log(rate) - rate - lgamma(h+2)), rate = exp(clip(tau + z.tauw, -8, 8))
__global__ __launch_bounds__(64) void k_hdist(const float* __restrict__ z,
                                              const float* __restrict__ tau,
                                              const float* __restrict__ tauw,
                                              float* __restrict__ h_dist) {
  const int bb = threadIdx.x;
  if (bb >= DB) return;
  float x = tau[0];
  for (int hy = 0; hy < DHY; ++hy) x = fmaf(z[bb * DHY + hy], tauw[hy], x);
  x = fminf(fmaxf(x, -8.f), 8.f);
  const float rate = __expf(x);
  const float lr = x;  // log(exp(clipped x)) == clipped x
  float lp[DH];
  float lg = 0.f;      // running log((h+1)!)
  float mx = -1e30f;
  #pragma unroll
  for (int h = 0; h < DH; ++h) {
    const float ks = (float)(h + 1);
    lg += __logf(ks);
    lp[h] = ks * lr - rate - lg;
    mx = fmaxf(mx, lp[h]);
  }
  float sum = 0.f;
  #pragma unroll
  for (int h = 0; h < DH; ++h) { lp[h] = __expf(lp[h] - mx); sum += lp[h]; }
  const float inv = 1.f / sum;
  #pragma unroll
  for (int h = 0; h < DH; ++h) h_dist[bb * DH + h] = lp[h] * inv;
}

// alpha_a = softmax(logp_u) over A. rows = T*B = 4096, 16 rows per wg.
__global__ __launch_bounds__(256) void k_alpha_a(const float* __restrict__ logp_u,
                                                 float* __restrict__ alpha_a) {
  const int row = blockIdx.x * 16 + (threadIdx.x >> 4);
  const int k = threadIdx.x & 15;
  const float v = logp_u[(size_t)row * DA + k];
  float m = v;
  #pragma unroll
  for (int o = 8; o >= 1; o >>= 1) m = fmaxf(m, __shfl_xor(m, o, 16));
  const float e = __expf(v - m);
  float s = e;
  #pragma unroll
  for (int o = 8; o >= 1; o >>= 1) s += __shfl_xor(s, o, 16);
  alpha_a[(size_t)row * DA + k] = e / s;
}

__global__ __launch_bounds__(256) void k_copyb(const float* __restrict__ bin,
                                               float* __restrict__ b_cur) {
  const int i = blockIdx.x * 256 + threadIdx.x;
  b_cur[i] = bin[i];
}

// transition[b,ki,j] = softmax_j(w[ki,j] + sum_hy z[b,hy]*wofs[(ki*S+j),hy]), stored fp16.
// one wg per ki (A*S = 4096 wgs), thread = j.
__global__ __launch_bounds__(256) void k_trans(const float* __restrict__ w,
                                               const float* __restrict__ wofs,
                                               const float* __restrict__ z,
                                               __half* __restrict__ trans) {
  const int ki = blockIdx.x;
  const int j = threadIdx.x;
  float wr[DHY];
  {
    const float4* w4 = reinterpret_cast<const float4*>(wofs + ((size_t)ki * DS + j) * DHY);
    #pragma unroll
    for (int q = 0; q < DHY / 4; ++q) {
      float4 v = w4[q];
      wr[4 * q] = v.x; wr[4 * q + 1] = v.y; wr[4 * q + 2] = v.z; wr[4 * q + 3] = v.w;
    }
  }
  const float wbase = w[(size_t)ki * DS + j];
  __shared__ float zs[DB * DHY];  // 16 KB
  for (int tt = threadIdx.x; tt < DB * DHY; tt += 256) zs[tt] = z[tt];
  __shared__ float red[4];
  __syncthreads();
  const int lane = threadIdx.x & 63;
  const int wid = threadIdx.x >> 6;
  __half* tout = trans + (size_t)ki * DS + j;
  for (int b = 0; b < DB; ++b) {
    float acc = wbase;
    const float* zb = &zs[b * DHY];
    #pragma unroll
    for (int hy = 0; hy < DHY; ++hy) acc = fmaf(zb[hy], wr[hy], acc);
    // logits are small (|acc| < ~1): softmax without max-subtract is safe
    const float e = __expf(acc);
    float v = e;
    #pragma unroll
    for (int o = 32; o >= 1; o >>= 1) v += __shfl_xor(v, o, 64);
    if (lane == 0) red[wid] = v;
    __syncthreads();
    const float s = red[0] + red[1] + red[2] + red[3];
    tout[(size_t)b * (DA * DS * DS)] = __float2half(e / s);
    __syncthreads();
  }
}

// ---------------- per-step kernels ----------------

// s_next[b,j] = sum_{k,i} trans[b,k,i,j] * b_cur[b,i] * alpha_a[t,b,k]
// grid = B*4 (b, j-chunk of 64). 256 threads: 8 lanes per row (8 j each), 32 rows/iter, 128 iters.
__global__ __launch_bounds__(256) void k_snext(const __half* __restrict__ trans,
                                               const float* __restrict__ b_cur,
                                               const float* __restrict__ alpha_a,
                                               float* __restrict__ s_next,
                                               float* __restrict__ out_pi,
                                               int t) {
  const int bb = blockIdx.x >> 2;
  const int jt = blockIdx.x & 3;
  const int tid = threadIdx.x;
  __shared__ float wv[DA * DS];  // a[k]*b[i], 16 KB
  __shared__ float sacc[64];
  const float* bt = b_cur + bb * DS;
  const float* at = alpha_a + ((size_t)t * DB + bb) * DA;
  for (int r = tid; r < DA * DS; r += 256) wv[r] = at[r >> 8] * bt[r & 255];
  if (tid < 64) sacc[tid] = 0.f;
  if (jt == 0 && tid < DA) out_pi[((size_t)t * DB + bb) * DA + tid] = 0.f;  // zero for k_plan atomics
  __syncthreads();
  const int jo = (tid & 7) * 8;  // j offset within chunk
  const int rb = tid >> 3;       // 0..31
  const __half* tb = trans + (size_t)bb * (DA * DS * DS) + jt * 64 + jo;
  float acc[8] = {0.f, 0.f, 0.f, 0.f, 0.f, 0.f, 0.f, 0.f};
  #pragma unroll 8
  for (int it = 0; it < 128; ++it) {
    const int r = it * 32 + rb;
    const float wgt = wv[r];
    union { int4 i4; __half2 h2[4]; } u;
    u.i4 = *reinterpret_cast<const int4*>(tb + (size_t)r * DS);
    #pragma unroll
    for (int q = 0; q < 4; ++q) {
      const float2 f = __half22float2(u.h2[q]);
      acc[2 * q]     = fmaf(wgt, f.x, acc[2 * q]);
      acc[2 * q + 1] = fmaf(wgt, f.y, acc[2 * q + 1]);
    }
  }
  #pragma unroll
  for (int q = 0; q < 8; ++q) {
    acc[q] += __shfl_xor(acc[q], 8, 64);
    acc[q] += __shfl_xor(acc[q], 16, 64);
    acc[q] += __shfl_xor(acc[q], 32, 64);
  }
  if ((tid & 63) < 8) {
    #pragma unroll
    for (int q = 0; q < 8; ++q) atomicAdd(&sacc[(tid & 7) * 8 + q], acc[q]);
  }
  __syncthreads();
  if (tid < 64) s_next[bb * DS + jt * 64 + tid] = sacc[tid];
}

// b_next = softmax(log(s_next+eps)+logp_o[t]); write alpha_b; plan: logits h,k -> softmax_k -> mix h_dist
// grid = B*4 (b, h-tile of 8). all wgs recompute b_next (cheap); ht==0 writes it.
__global__ __launch_bounds__(256) void k_plan(const float* __restrict__ s_next,
                                              const float* __restrict__ logp_o,
                                              const float* __restrict__ value,
                                              const float* __restrict__ h_dist,
                                              float* __restrict__ b_cur,
                                              float* __restrict__ out_b,
                                              float* __restrict__ out_pi,
                                              int t) {
  const int bb = blockIdx.x >> 2;
  const int ht = blockIdx.x & 3;
  const int tid = threadIdx.x;
  __shared__ float bl[DS];
  __shared__ float red[4];
  __shared__ float api[DA];
  const int lane = tid & 63;
  const int wid = tid >> 6;
  const float l = logf(s_next[bb * DS + tid] + 1e-6f) + logp_o[((size_t)t * DB + bb) * DS + tid];
  float m = l;
  #pragma unroll
  for (int o = 32; o >= 1; o >>= 1) m = fmaxf(m, __shfl_xor(m, o, 64));
  if (lane == 0) red[wid] = m;
  __syncthreads();
  m = fmaxf(fmaxf(red[0], red[1]), fmaxf(red[2], red[3]));
  __syncthreads();  // red reuse
  const float e = __expf(l - m);
  float v = e;
  #pragma unroll
  for (int o = 32; o >= 1; o >>= 1) v += __shfl_xor(v, o, 64);
  if (lane == 0) red[wid] = v;
  if (tid < DA) api[tid] = 0.f;
  __syncthreads();
  const float s = red[0] + red[1] + red[2] + red[3];
  const float p = e / s;
  bl[tid] = p;
  if (ht == 0) {
    out_b[((size_t)t * DB + bb) * DS + tid] = p;
    b_cur[bb * DS + tid] = p;
  }
  __syncthreads();
  // plan for h in [ht*8, ht*8+8): threads 0..127 hold (h_local = tid>>4, k = tid&15)
  const int hl = tid >> 4;
  const int k = tid & 15;
  const int h = ht * 8 + hl;
  float lg = -1e30f;
  if (hl < 8 && h < DH) {
    const float4* vr = reinterpret_cast<const float4*>(value + (((size_t)h * DB + bb) * DA + k) * DS);
    const float4* b4 = reinterpret_cast<const float4*>(bl);
    float acc = 0.f;
    #pragma unroll 8
    for (int q = 0; q < DS / 4; ++q) {
      const float4 a = vr[q];
      const float4 c = b4[q];
      acc += a.x * c.x + a.y * c.y + a.z * c.z + a.w * c.w;
    }
    lg = acc;
  }
  float mk = lg;
  #pragma unroll
  for (int o = 8; o >= 1; o >>= 1) mk = fmaxf(mk, __shfl_xor(mk, o, 16));
  const float ek = __expf(lg - mk);
  float sk = ek;
  #pragma unroll
  for (int o = 8; o >= 1; o >>= 1) sk += __shfl_xor(sk, o, 16);
  if (hl < 8 && h < DH) {
    const float ak = ek / sk;
    atomicAdd(&api[k], ak * h_dist[bb * DH + h]);
  }
  __syncthreads();
  if (tid < DA) atomicAdd(&out_pi[((size_t)t * DB + bb) * DA + tid], api[tid]);
}

// ---------------- launch ----------------

extern "C" void kernel_launch(void* const* d_in, const int* in_sizes, int n_in,
                              void* d_out, int out_size, void* d_ws, size_t ws_size,
                              hipStream_t stream) {
  const float* logp_o = (const float*)d_in[0];
  const float* logp_u = (const float*)d_in[1];
  const float* value  = (const float*)d_in[2];
  const float* z      = (const float*)d_in[3];
  const float* b0     = (const float*)d_in[4];
  const float* w      = (const float*)d_in[5];
  const float* wofs   = (const float*)d_in[6];
  const float* tau    = (const float*)d_in[7];
  const float* tauw   = (const float*)d_in[8];

  char* ws = (char*)d_ws;
  size_t off = 0;
  __half* trans  = (__half*)(ws + off); off += (size_t)DB * DA * DS * DS * sizeof(__half);
  float* s_next  = (float*)(ws + off);  off += (size_t)DB * DS * sizeof(float);
  float* b_cur   = (float*)(ws + off);  off += (size_t)DB * DS * sizeof(float);
  float* h_dist  = (float*)(ws + off);  off += (size_t)DB * DH * sizeof(float) + 64;
  float* alpha_a = (float*)(ws + off);  off += (size_t)DT * DB * DA * sizeof(float);
  if (off > ws_size) return;  // workspace too small -> visible failure

  float* out_b  = (float*)d_out;
  float* out_pi = out_b + (size_t)DT * DB * DS;

  k_hdist<<<1, 64, 0, stream>>>(z, tau, tauw, h_dist);
  k_alpha_a<<<256, 256, 0, stream>>>(logp_u, alpha_a);
  k_copyb<<<64, 256, 0, stream>>>(b0, b_cur);
  k_trans<<<DA * DS, 256, 0, stream>>>(w, wofs, z, trans);
  for (int t = 0; t < DT; ++t) {
    k_snext<<<DB * 4, 256, 0, stream>>>(trans, b_cur, alpha_a, s_next, out_pi, t);
    k_plan<<<DB * 4, 256, 0, stream>>>(s_next, logp_o, value, h_dist, b_cur, out_b, out_pi, t);
  }
}